// Round 1
// baseline (1201.945 us; speedup 1.0000x reference)
//
#include <hip/hip_runtime.h>

#define NUM_C 1000
#define DIM 128
#define MARGIN 0.1f

// ---------------- workspace layout ----------------
// [0      .. 4096)   counts  (u32[1024])
// [4096   .. 8192)   offsets (u32[1024])
// [8192   .. 12288)  cursor  (u32[1024])
// [12288  .. )       perm    (u32[N])

__global__ void k_init(unsigned* __restrict__ counts, float* __restrict__ out, int out_n) {
    int t = threadIdx.x;
    for (int i = t; i < 1024; i += blockDim.x) counts[i] = 0u;
    if (t < out_n) out[t] = 0.0f;
}

__global__ void k_hist(const int* __restrict__ label, unsigned* __restrict__ counts, int n) {
    __shared__ unsigned h[NUM_C];
    for (int i = threadIdx.x; i < NUM_C; i += blockDim.x) h[i] = 0u;
    __syncthreads();
    int idx = blockIdx.x * blockDim.x + threadIdx.x;
    int stride = gridDim.x * blockDim.x;
    for (int i = idx; i < n; i += stride) atomicAdd(&h[label[i]], 1u);
    __syncthreads();
    for (int i = threadIdx.x; i < NUM_C; i += blockDim.x) {
        unsigned v = h[i];
        if (v) atomicAdd(&counts[i], v);
    }
}

// single block, 1024 threads: exclusive scan of counts -> offsets, cursor
__global__ void k_scan(const unsigned* __restrict__ counts,
                       unsigned* __restrict__ offsets,
                       unsigned* __restrict__ cursor) {
    __shared__ unsigned s[1024];
    int t = threadIdx.x;
    unsigned v = (t < NUM_C) ? counts[t] : 0u;
    s[t] = v;
    __syncthreads();
    for (int off = 1; off < 1024; off <<= 1) {
        unsigned x = (t >= off) ? s[t - off] : 0u;
        __syncthreads();
        s[t] += x;
        __syncthreads();
    }
    if (t < NUM_C) {
        unsigned e = s[t] - v;   // exclusive
        offsets[t] = e;
        cursor[t] = e;
    }
}

__global__ void k_scatter(const int* __restrict__ label,
                          unsigned* __restrict__ cursor,
                          unsigned* __restrict__ perm, int n) {
    int idx = blockIdx.x * blockDim.x + threadIdx.x;
    int stride = gridDim.x * blockDim.x;
    for (int i = idx; i < n; i += stride) {
        int c = label[i];
        unsigned p = atomicAdd(&cursor[c], 1u);
        perm[p] = (unsigned)i;
    }
}

// one block per class, 256 threads = 4 waves
__launch_bounds__(256)
__global__ void k_main(const float* __restrict__ f1, const float* __restrict__ f2,
                       const unsigned* __restrict__ offsets,
                       const unsigned* __restrict__ counts,
                       const unsigned* __restrict__ perm,
                       float* __restrict__ out) {
    const int c = blockIdx.x;
    const unsigned start = offsets[c];
    const unsigned cnt = counts[c];
    const int wave = threadIdx.x >> 6;
    const int lane = threadIdx.x & 63;

    float a1x = 0.f, a1y = 0.f, a2x = 0.f, a2y = 0.f;

    auto body = [&](unsigned r) {
        unsigned row = perm[start + r];          // wave-uniform broadcast
        const float2* p1 = (const float2*)(f1 + (size_t)row * DIM);
        const float2* p2 = (const float2*)(f2 + (size_t)row * DIM);
        float2 v1 = p1[lane];
        float2 v2 = p2[lane];
        float s1 = v1.x * v1.x + v1.y * v1.y;
        float s2 = v2.x * v2.x + v2.y * v2.y;
        #pragma unroll
        for (int off = 32; off; off >>= 1) {
            s1 += __shfl_xor(s1, off);
            s2 += __shfl_xor(s2, off);
        }
        float i1 = 1.0f / sqrtf(s1);
        float i2 = 1.0f / sqrtf(s2);
        a1x += v1.x * i1; a1y += v1.y * i1;
        a2x += v2.x * i2; a2y += v2.y * i2;
    };

    unsigned r = (unsigned)wave;
    // unroll-2 for two independent load/reduce chains in flight per wave
    for (; r + 4 < cnt; r += 8) { body(r); body(r + 4); }
    for (; r < cnt; r += 4) { body(r); }

    __shared__ float lds1[4][DIM];
    __shared__ float lds2[4][DIM];
    lds1[wave][2 * lane]     = a1x;
    lds1[wave][2 * lane + 1] = a1y;
    lds2[wave][2 * lane]     = a2x;
    lds2[wave][2 * lane + 1] = a2y;
    __syncthreads();

    float sq = 0.f;
    if (threadIdx.x < DIM) {
        int d = threadIdx.x;
        float s1 = lds1[0][d] + lds1[1][d] + lds1[2][d] + lds1[3][d];
        float s2 = lds2[0][d] + lds2[1][d] + lds2[2][d] + lds2[3][d];
        float denom = fmaxf((float)cnt, 1.0f);
        float dif = (s1 - s2) / denom;
        sq = dif * dif;
    }
    #pragma unroll
    for (int off = 32; off; off >>= 1) sq += __shfl_xor(sq, off);

    __shared__ float partial[4];
    if (lane == 0) partial[wave] = sq;
    __syncthreads();
    if (threadIdx.x == 0) {
        float tot = partial[0] + partial[1];
        float h = tot - MARGIN;
        if (h > 0.f && cnt > 0u) atomicAdd(out, h);
    }
}

extern "C" void kernel_launch(void* const* d_in, const int* in_sizes, int n_in,
                              void* d_out, int out_size, void* d_ws, size_t ws_size,
                              hipStream_t stream) {
    const float* feat1 = (const float*)d_in[0];
    const float* feat2 = (const float*)d_in[1];
    const int* label = (const int*)d_in[2];
    const int n = in_sizes[2];                 // number of rows

    char* ws = (char*)d_ws;
    unsigned* counts  = (unsigned*)(ws + 0);
    unsigned* offsets = (unsigned*)(ws + 4096);
    unsigned* cursor  = (unsigned*)(ws + 8192);
    unsigned* perm    = (unsigned*)(ws + 12288);
    float* out = (float*)d_out;

    k_init<<<1, 256, 0, stream>>>(counts, out, out_size);
    k_hist<<<256, 256, 0, stream>>>(label, counts, n);
    k_scan<<<1, 1024, 0, stream>>>(counts, offsets, cursor);
    k_scatter<<<256, 256, 0, stream>>>(label, cursor, perm, n);
    k_main<<<NUM_C, 256, 0, stream>>>(feat1, feat2, offsets, counts, perm, out);
}